// Round 3
// baseline (362.985 us; speedup 1.0000x reference)
//
#include <hip/hip_runtime.h>
#include <math.h>

// (T,B,C,H,W) = (9,8,256,56,56), fp32.
// Round 3: occupancy/phase-diversity play. P=4 pixels/block -> 38.6 KB LDS
// -> 4 independent blocks/CU (was 2 at P=8). Rounds 0-2 showed the kernel's
// compute phases are hidden under HBM delivery, but the 2 co-resident blocks
// run in lockstep (launch together, barrier together) so HBM idles during
// every compute phase. 4 independent blocks/CU + 16 waves/CU keeps HBM fed.
// LDS swizzle: tile word index XOR ((t&1)<<4) — a bijection per t-slice:
//  - scores: lanes span 4 t's at the same (cp,px) bank -> split 2-way (free)
//  - stage writes / attend b128 reads: uniform bank coverage preserved.
// Math note (validated, absmax <= 1.6e-2): score_center and bias are
// constant along softmax axis t -> shift-invariant -> dropped.
#define TT 9
#define BN 8
#define CC 256
#define HW 3136
#define P 4               // pixels per block
#define NCHUNK (HW / P)   // 784
#define CENTER_T 4

__global__ __launch_bounds__(256, 4) void fused_stage_kernel(
    const float* __restrict__ seq, const float* __restrict__ w,
    const float* __restrict__ gamma, float* __restrict__ out) {
  // blk&7 -> batch b (= XCD b under %8 round-robin): the 8 blocks sharing
  // each 128B line are <=56 bids apart -> co-resident -> L2 merges reads
  // and writes into full lines.
  const int blk = blockIdx.x;
  const int b = blk & 7;
  const int chunk = blk >> 3;    // 0..783
  const int px0 = chunk * P;
  const int tid = threadIdx.x;

  __shared__ __align__(16) float tile[TT * CC * P];  // 36864 B, swizzled
  __shared__ float wsh[CC];
  __shared__ __align__(16) float red[36 * 4];        // 144 partials
  __shared__ __align__(16) float sc[TT * P];         // attn weights

  wsh[tid] = w[CC + tid];  // w_other

  // ---- Stage: thread = channel row; 9 float4 loads (t=0..8), issued
  // before any LDS write so the writes consume them with counted waits.
  {
    const float* sgb = seq + ((size_t)b * CC + tid) * HW + px0;
    float4 pre[TT];
#pragma unroll
    for (int t = 0; t < TT; ++t)
      pre[t] = *(const float4*)(sgb + (size_t)t * (BN * CC * HW));
#pragma unroll
    for (int t = 0; t < TT; ++t)
      *(float4*)(&tile[(t * 1024 + 4 * tid) ^ ((t & 1) << 4)]) = pre[t];
  }
  __syncthreads();

  // ---- Scores: 144 items = 36 (t,px) pairs x 4 interleaved c-partitions.
  // c = cp + 4*(j^(t&1)); tile word = t*1024 + 4cp + px + 16j (swizzle
  // folded into the j<->c pairing). Banks: (4cp+px)%16 + 16*(j&1 ^ t&1)
  // -> 2 lanes/bank (free).
  if (tid < 144) {
    const int cp = tid & 3;
    const int pair = tid >> 2;   // t*4 + px
    const int t = pair >> 2;
    const int px = pair & 3;
    const int e = t & 1;
    const int sbase = t * 1024 + 4 * cp + px;
    float a = 0.f;
#pragma unroll
    for (int j = 0; j < 64; ++j)
      a = fmaf(tile[sbase + 16 * j], wsh[cp + 4 * (j ^ e)], a);
    red[tid] = a;
  }
  __syncthreads();

  // ---- Reduce partials + softmax over t (one thread per pixel) ----
  if (tid < P) {
    const int px = tid;
    float vv[TT];
    float m = -1e30f;
#pragma unroll
    for (int t = 0; t < TT; ++t) {
      const float4 r = *(const float4*)(&red[(t * 4 + px) * 4]);
      const float s = (r.x + r.y) + (r.z + r.w);
      vv[t] = s;
      m = fmaxf(m, s);
    }
    float s = 0.f;
#pragma unroll
    for (int t = 0; t < TT; ++t) { vv[t] = __expf(vv[t] - m); s += vv[t]; }
    const float inv = 1.f / s;
#pragma unroll
    for (int t = 0; t < TT; ++t) sc[t * P + px] = vv[t] * inv;
  }
  __syncthreads();

  // ---- Attend: thread = channel, one float4 (4 px); sc reads broadcast ----
  {
    const int c = tid;
    float4 o = {0.f, 0.f, 0.f, 0.f};
    float4 cv = {0.f, 0.f, 0.f, 0.f};
#pragma unroll
    for (int t = 0; t < TT; ++t) {
      const float4 s = *(const float4*)(&sc[t * P]);
      const float4 v = *(const float4*)(&tile[(t * 1024 + 4 * c) ^ ((t & 1) << 4)]);
      o.x = fmaf(s.x, v.x, o.x);
      o.y = fmaf(s.y, v.y, o.y);
      o.z = fmaf(s.z, v.z, o.z);
      o.w = fmaf(s.w, v.w, o.w);
      if (t == CENTER_T) cv = v;
    }
    const float gm = gamma[0];
    float4 r;
    r.x = fmaf(gm, o.x, cv.x);
    r.y = fmaf(gm, o.y, cv.y);
    r.z = fmaf(gm, o.z, cv.z);
    r.w = fmaf(gm, o.w, cv.w);
    float* ob = out + ((size_t)b * CC + c) * HW + px0;
    *(float4*)(ob) = r;
  }
}

extern "C" void kernel_launch(void* const* d_in, const int* in_sizes, int n_in,
                              void* d_out, int out_size, void* d_ws, size_t ws_size,
                              hipStream_t stream) {
  const float* seq = (const float*)d_in[0];
  const float* w = (const float*)d_in[1];
  // d_in[2] (bias) unused: softmax shift-invariant.
  const float* gamma = (const float*)d_in[3];
  float* out = (float*)d_out;

  fused_stage_kernel<<<BN * NCHUNK, 256, 0, stream>>>(seq, w, gamma, out);
}